// Round 8
// baseline (302.500 us; speedup 1.0000x reference)
//
#include <hip/hip_runtime.h>
#include <hip/hip_bf16.h>

// Problem constants
#define HEADS   12
#define HD      64
#define NTOK    197          // N_PATCH + 1
#define BATCH   64
#define M_TOK   (BATCH*NTOK) // 12608
#define DIMC    768
#define NPAIR   (NTOK*NTOK)  // 38809
#define MPAD    224          // key/m dimension padded to 7*32

typedef __attribute__((ext_vector_type(8))) short bf16x8;  // 8 bf16 (4 VGPRs)
typedef __attribute__((ext_vector_type(4))) short s16x4;
typedef __attribute__((ext_vector_type(4))) float f32x4;

// fp32 -> bf16 round-to-nearest-even
static __device__ __forceinline__ short f2bf(float f) {
    unsigned u = __float_as_uint(f);
    unsigned r = (u + 0x7FFFu + ((u >> 16) & 1u)) >> 16;
    return (short)r;
}

// ---------------------------------------------------------------------------
// Kernel 0a: fused fp32 -> bf16 bulk convert of x, qkv_w, proj_w (one launch)
// ---------------------------------------------------------------------------
#define NX (M_TOK * DIMC)        // 9,682,944
#define NW (3 * DIMC * DIMC)     // 1,769,472
#define NP (DIMC * DIMC)         //   589,824
__global__ void cvt_kernel(const float* __restrict__ s0, short* __restrict__ d0,
                           const float* __restrict__ s1, short* __restrict__ d1,
                           const float* __restrict__ s2, short* __restrict__ d2) {
    int i = (blockIdx.x * 256 + threadIdx.x) * 4;
    const float* s; short* d;
    if (i < NX)                { s = s0 + i; d = d0 + i; }
    else if (i < NX + NW)      { s = s1 + (i - NX); d = d1 + (i - NX); }
    else if (i < NX + NW + NP) { s = s2 + (i - NX - NW); d = d2 + (i - NX - NW); }
    else return;
    const float4 v = *(const float4*)s;
    s16x4 b; b[0] = f2bf(v.x); b[1] = f2bf(v.y); b[2] = f2bf(v.z); b[3] = f2bf(v.w);
    *(s16x4*)d = b;
}

// ---------------------------------------------------------------------------
// Kernel 0b: expand rpb_table via rel_pos_index -> rpb_full[h][n*197+m]
// ---------------------------------------------------------------------------
__global__ void rpb_kernel(const float* __restrict__ table,
                           const int* __restrict__ idx,
                           float* __restrict__ rpb_full) {
    int i = blockIdx.x * 256 + threadIdx.x;
    if (i >= NPAIR) return;
    int id = idx[i];
    #pragma unroll
    for (int h = 0; h < HEADS; ++h)
        rpb_full[(size_t)h * NPAIR + i] = table[id * HEADS + h];
}

// ---------------------------------------------------------------------------
// 256x256 GEMM template: 8 waves (2Mx4N), BK=64, full-tile double buffer
// (4 x 32 KiB LDS), counted-vmcnt pipeline (T3+T4), swizzled LDS (T2),
// setprio around MFMA (T5).
// Schedule per K-tile: vmcnt(8) -> s_barrier -> compute -> s_barrier ->
// stage tile kt+2 into freed buffer. Loads stay in flight across barriers;
// vmcnt never drains to 0 in steady state.
// Swizzle (rule #21 both-sides): LDS dest linear (global_load_lds), global
// SOURCE chunk pre-permuted (l&7)^(l>>3), ds_read chunk = want ^ (row&7).
// ---------------------------------------------------------------------------
#define STAGE256(LA, LB, kt)                                                    \
    _Pragma("unroll")                                                           \
    for (int i = 0; i < 4; ++i) {                                               \
        __builtin_amdgcn_global_load_lds(                                       \
            (const __attribute__((address_space(1))) void*)(aptr[i] + (kt) * 64),\
            (__attribute__((address_space(3))) void*)&LA[(wv * 4 + i) * 512],   \
            16, 0, 0);                                                          \
        __builtin_amdgcn_global_load_lds(                                       \
            (const __attribute__((address_space(1))) void*)(bptr[i] + (kt) * 64),\
            (__attribute__((address_space(3))) void*)&LB[(wv * 4 + i) * 512],   \
            16, 0, 0);                                                          \
    }

#define COMPUTE256(LA, LB)                                                      \
    __builtin_amdgcn_s_setprio(1);                                              \
    _Pragma("unroll")                                                           \
    for (int ks = 0; ks < 2; ++ks) {                                            \
        bf16x8 af[8], bfr[4];                                                   \
        const int kk = (((ks * 4 + g) ^ (c16 & 7)) << 3);                       \
        _Pragma("unroll")                                                       \
        for (int i = 0; i < 8; ++i)                                             \
            af[i] = *(const bf16x8*)&LA[(wrr * 128 + i * 16 + c16) * 64 + kk];  \
        _Pragma("unroll")                                                       \
        for (int j = 0; j < 4; ++j)                                             \
            bfr[j] = *(const bf16x8*)&LB[(wcc * 64 + j * 16 + c16) * 64 + kk];  \
        _Pragma("unroll")                                                       \
        for (int i = 0; i < 8; ++i)                                             \
            _Pragma("unroll")                                                   \
            for (int j = 0; j < 4; ++j)                                         \
                acc[i][j] = __builtin_amdgcn_mfma_f32_16x16x32_bf16(            \
                    af[i], bfr[j], acc[i][j], 0, 0, 0);                         \
    }                                                                           \
    __builtin_amdgcn_s_setprio(0);

#define GEMM_PIPELINE()                                                         \
    STAGE256(lds_a0, lds_b0, 0);                                                \
    STAGE256(lds_a1, lds_b1, 1);                                                \
    _Pragma("unroll")                                                           \
    for (int kt = 0; kt < 12; ++kt) {                                           \
        if (kt == 11) { asm volatile("s_waitcnt vmcnt(0)" ::: "memory"); }      \
        else          { asm volatile("s_waitcnt vmcnt(8)" ::: "memory"); }      \
        __builtin_amdgcn_s_barrier();                                           \
        if (kt & 1) { COMPUTE256(lds_a1, lds_b1); }                             \
        else        { COMPUTE256(lds_a0, lds_b0); }                             \
        if (kt < 10) {                                                          \
            __builtin_amdgcn_s_barrier();                                       \
            if (kt & 1) { STAGE256(lds_a1, lds_b1, kt + 2); }                   \
            else        { STAGE256(lds_a0, lds_b0, kt + 2); }                   \
        }                                                                       \
    }

// ---------------------------------------------------------------------------
// Kernel 1: QKV GEMM (bf16 in), 256x256 tile, epilogue scatters q/k/v^T.
// Grid: 450 flat blocks (50 M x 9 N), m204 bijective XCD swizzle q=56 r=2.
// ---------------------------------------------------------------------------
__global__ __launch_bounds__(512, 2) void qkv_gemm_kernel(
    const short* __restrict__ xb, const short* __restrict__ wb,
    const float* __restrict__ qb, const float* __restrict__ vb,
    short* __restrict__ q_ws, short* __restrict__ k_ws,
    short* __restrict__ vt_ws) {
    __shared__ __align__(16) short lds_a0[256 * 64];
    __shared__ __align__(16) short lds_a1[256 * 64];
    __shared__ __align__(16) short lds_b0[256 * 64];
    __shared__ __align__(16) short lds_b1[256 * 64];
    const int tid  = threadIdx.x;
    const int lane = tid & 63;
    const int wv   = tid >> 6;           // 0..7
    const int wrr  = wv >> 2, wcc = wv & 3;
    // XCD-bijective decode: nwg=450, q=56, r=2
    const int flat = blockIdx.x;
    const int xcd  = flat & 7, pos = flat >> 3;
    const int swz  = ((xcd < 2) ? xcd * 57 : 114 + (xcd - 2) * 56) + pos;
    const int bm   = swz / 9, bn = swz - bm * 9;
    const int g    = lane >> 4, c16 = lane & 15;

    f32x4 acc[8][4] = {};

    const int lrow = lane >> 3;
    const int lcol = ((lane & 7) ^ lrow) * 8;     // inverse-swizzled source col
    const short* aptr[4];
    const short* bptr[4];
    #pragma unroll
    for (int i = 0; i < 4; ++i) {
        const int r  = (wv * 4 + i) * 8 + lrow;
        int gr = bm * 256 + r; if (gr > M_TOK - 1) gr = M_TOK - 1;
        aptr[i] = xb + (size_t)gr * DIMC + lcol;
        bptr[i] = wb + (size_t)(bn * 256 + r) * DIMC + lcol;
    }

    GEMM_PIPELINE();

    // epilogue: C/D layout col = lane&15, row = (lane>>4)*4 + reg  [m89-verified]
    #pragma unroll
    for (int i = 0; i < 8; ++i) {
        const int tbase = bm * 256 + wrr * 128 + i * 16 + (g << 2);
        #pragma unroll
        for (int j = 0; j < 4; ++j) {
            const int c     = bn * 256 + wcc * 64 + j * 16 + c16;
            const int which = c / DIMC;            // 0=q 1=k 2=v
            const int r     = c - which * DIMC;
            const int h     = r >> 6, d = r & 63;
            #pragma unroll
            for (int rg = 0; rg < 4; ++rg) {
                const int tt = tbase + rg;
                if (tt >= M_TOK) continue;
                const int b = tt / NTOK, n = tt - b * NTOK;
                const size_t bh = (size_t)b * HEADS + h;
                float val = acc[i][j][rg];
                if (which == 0) {
                    val = (val + qb[r]) * 0.125f;                    // q scale hd^-0.5
                    q_ws[(bh * NTOK + n) * HD + d] = f2bf(val);
                } else if (which == 1) {
                    k_ws[(bh * NTOK + n) * HD + d] = f2bf(val);
                } else {
                    val += vb[r];
                    vt_ws[(bh * HD + d) * MPAD + n] = f2bf(val);     // transposed for PV B-frags
                }
            }
        }
    }
}

// ---------------------------------------------------------------------------
// Kernel 2: attention. 1 wave per (b,h, 16-row tile) — high TLP; Q/K/V read
// straight from global. XCD-aware id remap: all 13 row-tile blocks of one
// (b,h) share id mod 8 -> same XCD -> K/V/rpb stay in that XCD's L2.
// grid = 9984 = 8 * 13 * 96.
// ---------------------------------------------------------------------------
__global__ __launch_bounds__(64) void attn_kernel(
    const short* __restrict__ q_ws, const short* __restrict__ k_ws,
    const short* __restrict__ vt_ws, const float* __restrict__ rpb_full,
    short* __restrict__ o_ws) {
    __shared__ __align__(16) short p_lds[16 * 232];   // rows padded to 232
    const int lane = threadIdx.x;
    const int id   = blockIdx.x;
    const int slot = id & 7;                          // XCD (round-robin heuristic)
    const int rest = id >> 3;                         // 0..1247
    const int rt   = rest % 13;                       // row tile 0..12
    const int bh   = (rest / 13) * 8 + slot;          // 0..767 (bijective)
    const int b    = bh / HEADS, h = bh - b * HEADS;
    const int g    = lane >> 4, c16 = lane & 15;

    bf16x8 qa0, qa1;
    {
        const size_t base = ((size_t)bh * NTOK + (rt * 16 + c16)) * HD + g * 8;
        qa0 = *(const bf16x8*)(q_ws + base);
        qa1 = *(const bf16x8*)(q_ws + base + 32);
    }

    f32x4 sacc[14];
    #pragma unroll
    for (int t = 0; t < 14; ++t) sacc[t] = (f32x4){0.f, 0.f, 0.f, 0.f};
    #pragma unroll
    for (int mt = 0; mt < 14; ++mt) {
        const size_t base = ((size_t)bh * NTOK + (mt * 16 + c16)) * HD + g * 8;
        bf16x8 kb0 = *(const bf16x8*)(k_ws + base);
        bf16x8 kb1 = *(const bf16x8*)(k_ws + base + 32);
        sacc[mt] = __builtin_amdgcn_mfma_f32_16x16x32_bf16(qa0, kb0, sacc[mt], 0, 0, 0);
        sacc[mt] = __builtin_amdgcn_mfma_f32_16x16x32_bf16(qa1, kb1, sacc[mt], 0, 0, 0);
    }

    float mx[4] = {-1e30f, -1e30f, -1e30f, -1e30f};
    #pragma unroll
    for (int rg = 0; rg < 4; ++rg) {
        const int n = rt * 16 + g * 4 + rg;
        #pragma unroll
        for (int mt = 0; mt < 14; ++mt) {
            const int m = mt * 16 + c16;
            float s = sacc[mt][rg];
            if (n < NTOK && m < NTOK) s += rpb_full[(size_t)h * NPAIR + n * NTOK + m];
            else                      s = -1e30f;
            sacc[mt][rg] = s;
            mx[rg] = fmaxf(mx[rg], s);
        }
    }
    #pragma unroll
    for (int off = 1; off < 16; off <<= 1)
        #pragma unroll
        for (int rg = 0; rg < 4; ++rg)
            mx[rg] = fmaxf(mx[rg], __shfl_xor(mx[rg], off, 64));

    float sm[4] = {0.f, 0.f, 0.f, 0.f};
    #pragma unroll
    for (int mt = 0; mt < 14; ++mt)
        #pragma unroll
        for (int rg = 0; rg < 4; ++rg) {
            float p = exp2f((sacc[mt][rg] - mx[rg]) * 1.44269504f);
            sm[rg] += p;
            p_lds[(g * 4 + rg) * 232 + mt * 16 + c16] = f2bf(p);
        }
    #pragma unroll
    for (int off = 1; off < 16; off <<= 1)
        #pragma unroll
        for (int rg = 0; rg < 4; ++rg)
            sm[rg] += __shfl_xor(sm[rg], off, 64);
    __syncthreads();

    f32x4 oacc[4] = {};
    #pragma unroll
    for (int ks = 0; ks < 7; ++ks) {
        const int kk = ks * 32 + g * 8;
        bf16x8 pa = *(const bf16x8*)&p_lds[c16 * 232 + kk];
        #pragma unroll
        for (int j = 0; j < 4; ++j) {
            const int d = j * 16 + c16;
            bf16x8 vbf = *(const bf16x8*)(vt_ws + ((size_t)bh * HD + d) * MPAD + kk);
            oacc[j] = __builtin_amdgcn_mfma_f32_16x16x32_bf16(pa, vbf, oacc[j], 0, 0, 0);
        }
    }

    #pragma unroll
    for (int rg = 0; rg < 4; ++rg) {
        const int n = rt * 16 + g * 4 + rg;
        if (n >= NTOK) continue;
        const float inv = 1.0f / sm[rg];
        #pragma unroll
        for (int j = 0; j < 4; ++j)
            o_ws[((size_t)(b * NTOK + n)) * DIMC + h * HD + j * 16 + c16] =
                f2bf(oacc[j][rg] * inv);
    }
}

// ---------------------------------------------------------------------------
// Kernel 3: proj GEMM (o_ws bf16 @ pw_bf^T + proj_b) -> fp32 out; 256x256
// counted-vmcnt pipeline. Grid: 150 flat blocks (50 M x 3 N), swizzle q=18 r=6.
// ---------------------------------------------------------------------------
__global__ __launch_bounds__(512, 2) void proj_gemm_kernel(
    const short* __restrict__ a, const short* __restrict__ wb,
    const float* __restrict__ pb, float* __restrict__ out) {
    __shared__ __align__(16) short lds_a0[256 * 64];
    __shared__ __align__(16) short lds_a1[256 * 64];
    __shared__ __align__(16) short lds_b0[256 * 64];
    __shared__ __align__(16) short lds_b1[256 * 64];
    const int tid  = threadIdx.x;
    const int lane = tid & 63;
    const int wv   = tid >> 6;
    const int wrr  = wv >> 2, wcc = wv & 3;
    // XCD-bijective decode: nwg=150, q=18, r=6
    const int flat = blockIdx.x;
    const int xcd  = flat & 7, pos = flat >> 3;
    const int swz  = ((xcd < 6) ? xcd * 19 : 114 + (xcd - 6) * 18) + pos;
    const int bm   = swz / 3, bn = swz - bm * 3;
    const int g    = lane >> 4, c16 = lane & 15;

    f32x4 acc[8][4] = {};

    const int lrow = lane >> 3;
    const int lcol = ((lane & 7) ^ lrow) * 8;     // inverse-swizzled source col
    const short* aptr[4];
    const short* bptr[4];
    #pragma unroll
    for (int i = 0; i < 4; ++i) {
        const int r  = (wv * 4 + i) * 8 + lrow;
        int gr = bm * 256 + r; if (gr > M_TOK - 1) gr = M_TOK - 1;
        aptr[i] = a  + (size_t)gr * DIMC + lcol;
        bptr[i] = wb + (size_t)(bn * 256 + r) * DIMC + lcol;
    }

    GEMM_PIPELINE();

    #pragma unroll
    for (int i = 0; i < 8; ++i) {
        const int tbase = bm * 256 + wrr * 128 + i * 16 + (g << 2);
        #pragma unroll
        for (int j = 0; j < 4; ++j) {
            const int c   = bn * 256 + wcc * 64 + j * 16 + c16;
            const float bias = pb[c];
            #pragma unroll
            for (int rg = 0; rg < 4; ++rg) {
                const int tt = tbase + rg;
                if (tt >= M_TOK) continue;
                out[(size_t)tt * DIMC + c] = acc[i][j][rg] + bias;
            }
        }
    }
}

// ---------------------------------------------------------------------------
// Workspace layout (bytes):
//   q_ws   : 19,368,192   @ 0
//   k_ws   : 19,368,192   @ 19,368,192
//   vt_ws  : 22,020,096   @ 38,736,384
//   x_bf / o_ws : 19,365,888 @ 60,756,480  (aliased: x_bf dead before attn)
//   rpb    :  1,862,832   @ 80,122,368
//   w_bf   :  3,538,944   @ 81,985,200
//   pw_bf  :  1,179,648   @ 85,524,144    total 86,703,792
// ---------------------------------------------------------------------------
extern "C" void kernel_launch(void* const* d_in, const int* in_sizes, int n_in,
                              void* d_out, int out_size, void* d_ws, size_t ws_size,
                              hipStream_t stream) {
    const float* x       = (const float*)d_in[0];
    const float* qkv_w   = (const float*)d_in[1];
    const float* q_bias  = (const float*)d_in[2];
    const float* v_bias  = (const float*)d_in[3];
    const float* rpb_tab = (const float*)d_in[4];
    const float* proj_w  = (const float*)d_in[5];
    const float* proj_b  = (const float*)d_in[6];
    const int*   rel_idx = (const int*)d_in[7];
    float* out = (float*)d_out;

    char* ws = (char*)d_ws;
    short* q_ws     = (short*)(ws);
    short* k_ws     = (short*)(ws + 19368192);
    short* vt_ws    = (short*)(ws + 38736384);
    short* x_bf     = (short*)(ws + 60756480);   // aliased with o_ws
    short* o_ws     = (short*)(ws + 60756480);
    float* rpb_full = (float*)(ws + 80122368);
    short* w_bf     = (short*)(ws + 81985200);
    short* pw_bf    = (short*)(ws + 85524144);

    const int ncvt = (NX + NW + NP) / 4;  // 3,010,560 float4 elements
    cvt_kernel<<<(ncvt + 255) / 256, 256, 0, stream>>>(x, x_bf, qkv_w, w_bf, proj_w, pw_bf);
    rpb_kernel<<<(NPAIR + 255) / 256, 256, 0, stream>>>(rpb_tab, rel_idx, rpb_full);

    qkv_gemm_kernel<<<450, 512, 0, stream>>>(x_bf, w_bf, q_bias, v_bias,
                                             q_ws, k_ws, vt_ws);
    attn_kernel<<<9984, 64, 0, stream>>>(q_ws, k_ws, vt_ws, rpb_full, o_ws);
    proj_gemm_kernel<<<150, 512, 0, stream>>>(o_ws, pw_bf, proj_b, out);
}

// Round 9
// 223.662 us; speedup vs baseline: 1.3525x; 1.3525x over previous
//
#include <hip/hip_runtime.h>
#include <hip/hip_bf16.h>

// Problem constants
#define HEADS   12
#define HD      64
#define NTOK    197          // N_PATCH + 1
#define BATCH   64
#define M_TOK   (BATCH*NTOK) // 12608
#define DIMC    768
#define NPAIR   (NTOK*NTOK)  // 38809
#define MPAD    224          // key/m dimension padded to 7*32

typedef __attribute__((ext_vector_type(8))) short bf16x8;  // 8 bf16 (4 VGPRs)
typedef __attribute__((ext_vector_type(4))) short s16x4;
typedef __attribute__((ext_vector_type(4))) float f32x4;

// fp32 -> bf16 round-to-nearest-even
static __device__ __forceinline__ short f2bf(float f) {
    unsigned u = __float_as_uint(f);
    unsigned r = (u + 0x7FFFu + ((u >> 16) & 1u)) >> 16;
    return (short)r;
}

// ---------------------------------------------------------------------------
// Kernel 0a: fused fp32 -> bf16 bulk convert of x, qkv_w, proj_w (one launch)
// ---------------------------------------------------------------------------
#define NX (M_TOK * DIMC)        // 9,682,944
#define NW (3 * DIMC * DIMC)     // 1,769,472
#define NP (DIMC * DIMC)         //   589,824
__global__ void cvt_kernel(const float* __restrict__ s0, short* __restrict__ d0,
                           const float* __restrict__ s1, short* __restrict__ d1,
                           const float* __restrict__ s2, short* __restrict__ d2) {
    int i = (blockIdx.x * 256 + threadIdx.x) * 4;
    const float* s; short* d;
    if (i < NX)                { s = s0 + i; d = d0 + i; }
    else if (i < NX + NW)      { s = s1 + (i - NX); d = d1 + (i - NX); }
    else if (i < NX + NW + NP) { s = s2 + (i - NX - NW); d = d2 + (i - NX - NW); }
    else return;
    const float4 v = *(const float4*)s;
    s16x4 b; b[0] = f2bf(v.x); b[1] = f2bf(v.y); b[2] = f2bf(v.z); b[3] = f2bf(v.w);
    *(s16x4*)d = b;
}

// ---------------------------------------------------------------------------
// Kernel 0b: expand rpb_table via rel_pos_index -> rpb_full[h][n*197+m]
// ---------------------------------------------------------------------------
__global__ void rpb_kernel(const float* __restrict__ table,
                           const int* __restrict__ idx,
                           float* __restrict__ rpb_full) {
    int i = blockIdx.x * 256 + threadIdx.x;
    if (i >= NPAIR) return;
    int id = idx[i];
    #pragma unroll
    for (int h = 0; h < HEADS; ++h)
        rpb_full[(size_t)h * NPAIR + i] = table[id * HEADS + h];
}

// ---------------------------------------------------------------------------
// Shared GEMM building blocks (R7 config — measured best): 128x128 tile,
// BK=64, 4 waves of 64x64, 2-phase double-buffered staging.
// Bank-conflict fix (rule #21): LDS dest LINEAR (global_load_lds requirement),
// global SOURCE chunk pre-permuted (l&7)^(l>>3), ds_read chunk = want^(row&7).
// Measured: SQ_LDS_BANK_CONFLICT = 0.
// ---------------------------------------------------------------------------
#define STAGE(LA, LB, kt)                                                       \
    _Pragma("unroll")                                                           \
    for (int i = 0; i < 4; ++i) {                                               \
        __builtin_amdgcn_global_load_lds(                                       \
            (const __attribute__((address_space(1))) void*)(aptr[i] + (kt) * 64),\
            (__attribute__((address_space(3))) void*)&LA[(wv * 4 + i) * 512],   \
            16, 0, 0);                                                          \
        __builtin_amdgcn_global_load_lds(                                       \
            (const __attribute__((address_space(1))) void*)(bptr[i] + (kt) * 64),\
            (__attribute__((address_space(3))) void*)&LB[(wv * 4 + i) * 512],   \
            16, 0, 0);                                                          \
    }

#define COMPUTE(LA, LB)                                                         \
    _Pragma("unroll")                                                           \
    for (int ks = 0; ks < 2; ++ks) {                                            \
        bf16x8 af[4], bfr[4];                                                   \
        const int kk = (((ks * 4 + g) ^ (c16 & 7)) << 3);   /* swizzled read */ \
        _Pragma("unroll")                                                       \
        for (int i = 0; i < 4; ++i)                                             \
            af[i] = *(const bf16x8*)&LA[(wr * 64 + i * 16 + c16) * 64 + kk];    \
        _Pragma("unroll")                                                       \
        for (int j = 0; j < 4; ++j)                                             \
            bfr[j] = *(const bf16x8*)&LB[(wc * 64 + j * 16 + c16) * 64 + kk];   \
        _Pragma("unroll")                                                       \
        for (int i = 0; i < 4; ++i)                                             \
            _Pragma("unroll")                                                   \
            for (int j = 0; j < 4; ++j)                                         \
                acc[i][j] = __builtin_amdgcn_mfma_f32_16x16x32_bf16(            \
                    af[i], bfr[j], acc[i][j], 0, 0, 0);                         \
    }

// ---------------------------------------------------------------------------
// Kernel 1: QKV GEMM (bf16 in), epilogue scatters q (scaled), k, v^T.
// Grid: 1782 flat blocks, m204 bijective XCD swizzle (q=222, r=6).
// ---------------------------------------------------------------------------
__global__ __launch_bounds__(256) void qkv_gemm_kernel(
    const short* __restrict__ xb, const short* __restrict__ wb,
    const float* __restrict__ qb, const float* __restrict__ vb,
    short* __restrict__ q_ws, short* __restrict__ k_ws,
    short* __restrict__ vt_ws) {
    __shared__ __align__(16) short lds_a0[128 * 64];
    __shared__ __align__(16) short lds_a1[128 * 64];
    __shared__ __align__(16) short lds_b0[128 * 64];
    __shared__ __align__(16) short lds_b1[128 * 64];
    const int tid  = threadIdx.x;
    const int lane = tid & 63;
    const int wv   = tid >> 6;           // 0..3
    const int wr   = wv >> 1, wc = wv & 1;
    // XCD-bijective decode: nwg=1782, q=222, r=6
    const int flat = blockIdx.x;
    const int xcd  = flat & 7, pos = flat >> 3;
    const int swz  = ((xcd < 6) ? xcd * 223 : 1338 + (xcd - 6) * 222) + pos;
    const int bm   = swz / 18, bn = swz - bm * 18;
    const int g    = lane >> 4, c16 = lane & 15;

    f32x4 acc[4][4] = {};

    const int lrow = lane >> 3;
    const int lcol = ((lane & 7) ^ lrow) * 8;     // inverse-swizzled source col
    const short* aptr[4];
    const short* bptr[4];
    #pragma unroll
    for (int i = 0; i < 4; ++i) {
        const int r  = (wv * 4 + i) * 8 + lrow;
        int gr = bm * 128 + r; if (gr > M_TOK - 1) gr = M_TOK - 1;
        aptr[i] = xb + (size_t)gr * DIMC + lcol;
        bptr[i] = wb + (size_t)(bn * 128 + r) * DIMC + lcol;
    }

    STAGE(lds_a0, lds_b0, 0);
    __syncthreads();
    #pragma unroll
    for (int kp = 0; kp < 6; ++kp) {
        STAGE(lds_a1, lds_b1, 2 * kp + 1);
        COMPUTE(lds_a0, lds_b0);
        __syncthreads();
        if (kp < 5) { STAGE(lds_a0, lds_b0, 2 * kp + 2); }
        COMPUTE(lds_a1, lds_b1);
        if (kp < 5) __syncthreads();
    }

    // epilogue: C/D layout col = lane&15, row = (lane>>4)*4 + reg  [m89-verified]
    #pragma unroll
    for (int i = 0; i < 4; ++i) {
        const int tbase = bm * 128 + wr * 64 + i * 16 + (g << 2);
        #pragma unroll
        for (int j = 0; j < 4; ++j) {
            const int c     = bn * 128 + wc * 64 + j * 16 + c16;
            const int which = c / DIMC;            // 0=q 1=k 2=v
            const int r     = c - which * DIMC;
            const int h     = r >> 6, d = r & 63;
            #pragma unroll
            for (int rg = 0; rg < 4; ++rg) {
                const int tt = tbase + rg;
                if (tt >= M_TOK) continue;
                const int b = tt / NTOK, n = tt - b * NTOK;
                const size_t bh = (size_t)b * HEADS + h;
                float val = acc[i][j][rg];
                if (which == 0) {
                    val = (val + qb[r]) * 0.125f;                    // q scale hd^-0.5
                    q_ws[(bh * NTOK + n) * HD + d] = f2bf(val);
                } else if (which == 1) {
                    k_ws[(bh * NTOK + n) * HD + d] = f2bf(val);
                } else {
                    val += vb[r];
                    vt_ws[(bh * HD + d) * MPAD + n] = f2bf(val);     // transposed for PV B-frags
                }
            }
        }
    }
}

// ---------------------------------------------------------------------------
// Kernel 2: attention. 1 wave per (b,h, 16-row tile), XCD remap (all 13 tiles
// of one bh on one XCD). NEW: register-BATCHED loads for MLP — all 28 K frags,
// then 56 rpb, then 28 V frags issued as independent batches so each wave
// pays ~3 memory latencies instead of ~80 serialized ones (R4: 77k cy/wave
// stall at VGPR=68 — compiler kept too few loads in flight).
// ---------------------------------------------------------------------------
__global__ __launch_bounds__(64) void attn_kernel(
    const short* __restrict__ q_ws, const short* __restrict__ k_ws,
    const short* __restrict__ vt_ws, const float* __restrict__ rpb_full,
    short* __restrict__ o_ws) {
    __shared__ __align__(16) short p_lds[16 * 232];   // rows padded to 232
    const int lane = threadIdx.x;
    const int id   = blockIdx.x;
    const int slot = id & 7;                          // XCD (round-robin heuristic)
    const int rest = id >> 3;                         // 0..1247
    const int rt   = rest % 13;                       // row tile 0..12
    const int bh   = (rest / 13) * 8 + slot;          // 0..767 (bijective)
    const int b    = bh / HEADS, h = bh - b * HEADS;
    const int g    = lane >> 4, c16 = lane & 15;

    // Q fragments
    bf16x8 qa0, qa1;
    {
        const size_t base = ((size_t)bh * NTOK + (rt * 16 + c16)) * HD + g * 8;
        qa0 = *(const bf16x8*)(q_ws + base);
        qa1 = *(const bf16x8*)(q_ws + base + 32);
    }

    // ---- batch 1: all 28 K fragments (independent -> single latency) ----
    bf16x8 kb0[14], kb1[14];
    #pragma unroll
    for (int mt = 0; mt < 14; ++mt) {
        const size_t base = ((size_t)bh * NTOK + (mt * 16 + c16)) * HD + g * 8;
        kb0[mt] = *(const bf16x8*)(k_ws + base);
        kb1[mt] = *(const bf16x8*)(k_ws + base + 32);
    }

    f32x4 sacc[14];
    #pragma unroll
    for (int t = 0; t < 14; ++t) sacc[t] = (f32x4){0.f, 0.f, 0.f, 0.f};
    #pragma unroll
    for (int mt = 0; mt < 14; ++mt) {
        sacc[mt] = __builtin_amdgcn_mfma_f32_16x16x32_bf16(qa0, kb0[mt], sacc[mt], 0, 0, 0);
        sacc[mt] = __builtin_amdgcn_mfma_f32_16x16x32_bf16(qa1, kb1[mt], sacc[mt], 0, 0, 0);
    }

    // ---- batch 2: all 56 rpb values (clamped addresses, masked below) ----
    float rp[4][14];
    #pragma unroll
    for (int rg = 0; rg < 4; ++rg) {
        int n = rt * 16 + g * 4 + rg; int nc = n > NTOK - 1 ? NTOK - 1 : n;
        const float* rbase = rpb_full + (size_t)h * NPAIR + nc * NTOK;
        #pragma unroll
        for (int mt = 0; mt < 14; ++mt) {
            int m = mt * 16 + c16; int mc = m > NTOK - 1 ? NTOK - 1 : m;
            rp[rg][mt] = rbase[mc];
        }
    }

    float mx[4] = {-1e30f, -1e30f, -1e30f, -1e30f};
    #pragma unroll
    for (int rg = 0; rg < 4; ++rg) {
        const int n = rt * 16 + g * 4 + rg;
        #pragma unroll
        for (int mt = 0; mt < 14; ++mt) {
            const int m = mt * 16 + c16;
            float s = (n < NTOK && m < NTOK) ? sacc[mt][rg] + rp[rg][mt] : -1e30f;
            sacc[mt][rg] = s;
            mx[rg] = fmaxf(mx[rg], s);
        }
    }
    #pragma unroll
    for (int off = 1; off < 16; off <<= 1)
        #pragma unroll
        for (int rg = 0; rg < 4; ++rg)
            mx[rg] = fmaxf(mx[rg], __shfl_xor(mx[rg], off, 64));

    float sm[4] = {0.f, 0.f, 0.f, 0.f};
    #pragma unroll
    for (int mt = 0; mt < 14; ++mt)
        #pragma unroll
        for (int rg = 0; rg < 4; ++rg) {
            float p = exp2f((sacc[mt][rg] - mx[rg]) * 1.44269504f);
            sm[rg] += p;
            p_lds[(g * 4 + rg) * 232 + mt * 16 + c16] = f2bf(p);
        }

    // ---- batch 3: all 28 V fragments (overlap with sum-reduce + waitcnt) ----
    bf16x8 vbf[7][4];
    #pragma unroll
    for (int ks = 0; ks < 7; ++ks)
        #pragma unroll
        for (int j = 0; j < 4; ++j)
            vbf[ks][j] = *(const bf16x8*)(vt_ws +
                ((size_t)bh * HD + j * 16 + c16) * MPAD + ks * 32 + g * 8);

    #pragma unroll
    for (int off = 1; off < 16; off <<= 1)
        #pragma unroll
        for (int rg = 0; rg < 4; ++rg)
            sm[rg] += __shfl_xor(sm[rg], off, 64);
    __syncthreads();

    f32x4 oacc[4] = {};
    #pragma unroll
    for (int ks = 0; ks < 7; ++ks) {
        const int kk = ks * 32 + g * 8;
        bf16x8 pa = *(const bf16x8*)&p_lds[c16 * 232 + kk];
        #pragma unroll
        for (int j = 0; j < 4; ++j)
            oacc[j] = __builtin_amdgcn_mfma_f32_16x16x32_bf16(pa, vbf[ks][j], oacc[j], 0, 0, 0);
    }

    #pragma unroll
    for (int rg = 0; rg < 4; ++rg) {
        const int n = rt * 16 + g * 4 + rg;
        if (n >= NTOK) continue;
        const float inv = 1.0f / sm[rg];
        #pragma unroll
        for (int j = 0; j < 4; ++j)
            o_ws[((size_t)(b * NTOK + n)) * DIMC + h * HD + j * 16 + c16] =
                f2bf(oacc[j][rg] * inv);
    }
}

// ---------------------------------------------------------------------------
// Kernel 3: proj GEMM (o_ws bf16 @ pw_bf^T + proj_b) -> fp32 out; 2-phase dbuf
// Grid: 594 flat blocks, XCD swizzle (q=74, r=2).
// ---------------------------------------------------------------------------
__global__ __launch_bounds__(256) void proj_gemm_kernel(
    const short* __restrict__ a, const short* __restrict__ wb,
    const float* __restrict__ pb, float* __restrict__ out) {
    __shared__ __align__(16) short lds_a0[128 * 64];
    __shared__ __align__(16) short lds_a1[128 * 64];
    __shared__ __align__(16) short lds_b0[128 * 64];
    __shared__ __align__(16) short lds_b1[128 * 64];
    const int tid  = threadIdx.x;
    const int lane = tid & 63;
    const int wv   = tid >> 6;
    const int wr   = wv >> 1, wc = wv & 1;
    // XCD-bijective decode: nwg=594, q=74, r=2
    const int flat = blockIdx.x;
    const int xcd  = flat & 7, pos = flat >> 3;
    const int swz  = ((xcd < 2) ? xcd * 75 : 150 + (xcd - 2) * 74) + pos;
    const int bm   = swz / 6, bn = swz - bm * 6;
    const int g    = lane >> 4, c16 = lane & 15;

    f32x4 acc[4][4] = {};

    const int lrow = lane >> 3;
    const int lcol = ((lane & 7) ^ lrow) * 8;     // inverse-swizzled source col
    const short* aptr[4];
    const short* bptr[4];
    #pragma unroll
    for (int i = 0; i < 4; ++i) {
        const int r  = (wv * 4 + i) * 8 + lrow;
        int gr = bm * 128 + r; if (gr > M_TOK - 1) gr = M_TOK - 1;
        aptr[i] = a  + (size_t)gr * DIMC + lcol;
        bptr[i] = wb + (size_t)(bn * 128 + r) * DIMC + lcol;
    }

    STAGE(lds_a0, lds_b0, 0);
    __syncthreads();
    #pragma unroll
    for (int kp = 0; kp < 6; ++kp) {
        STAGE(lds_a1, lds_b1, 2 * kp + 1);
        COMPUTE(lds_a0, lds_b0);
        __syncthreads();
        if (kp < 5) { STAGE(lds_a0, lds_b0, 2 * kp + 2); }
        COMPUTE(lds_a1, lds_b1);
        if (kp < 5) __syncthreads();
    }

    #pragma unroll
    for (int i = 0; i < 4; ++i) {
        const int tbase = bm * 128 + wr * 64 + i * 16 + (g << 2);
        #pragma unroll
        for (int j = 0; j < 4; ++j) {
            const int c   = bn * 128 + wc * 64 + j * 16 + c16;
            const float bias = pb[c];
            #pragma unroll
            for (int rg = 0; rg < 4; ++rg) {
                const int tt = tbase + rg;
                if (tt >= M_TOK) continue;
                out[(size_t)tt * DIMC + c] = acc[i][j][rg] + bias;
            }
        }
    }
}

// ---------------------------------------------------------------------------
// Workspace layout (bytes):
//   q_ws   : 19,368,192   @ 0
//   k_ws   : 19,368,192   @ 19,368,192
//   vt_ws  : 22,020,096   @ 38,736,384
//   x_bf / o_ws : 19,365,888 @ 60,756,480  (aliased: x_bf dead before attn)
//   rpb    :  1,862,832   @ 80,122,368
//   w_bf   :  3,538,944   @ 81,985,200
//   pw_bf  :  1,179,648   @ 85,524,144    total 86,703,792
// ---------------------------------------------------------------------------
extern "C" void kernel_launch(void* const* d_in, const int* in_sizes, int n_in,
                              void* d_out, int out_size, void* d_ws, size_t ws_size,
                              hipStream_t stream) {
    const float* x       = (const float*)d_in[0];
    const float* qkv_w   = (const float*)d_in[1];
    const float* q_bias  = (const float*)d_in[2];
    const float* v_bias  = (const float*)d_in[3];
    const float* rpb_tab = (const float*)d_in[4];
    const float* proj_w  = (const float*)d_in[5];
    const float* proj_b  = (const float*)d_in[6];
    const int*   rel_idx = (const int*)d_in[7];
    float* out = (float*)d_out;

    char* ws = (char*)d_ws;
    short* q_ws     = (short*)(ws);
    short* k_ws     = (short*)(ws + 19368192);
    short* vt_ws    = (short*)(ws + 38736384);
    short* x_bf     = (short*)(ws + 60756480);   // aliased with o_ws
    short* o_ws     = (short*)(ws + 60756480);
    float* rpb_full = (float*)(ws + 80122368);
    short* w_bf     = (short*)(ws + 81985200);
    short* pw_bf    = (short*)(ws + 85524144);

    const int ncvt = (NX + NW + NP) / 4;  // 3,010,560 float4 elements
    cvt_kernel<<<(ncvt + 255) / 256, 256, 0, stream>>>(x, x_bf, qkv_w, w_bf, proj_w, pw_bf);
    rpb_kernel<<<(NPAIR + 255) / 256, 256, 0, stream>>>(rpb_tab, rel_idx, rpb_full);

    qkv_gemm_kernel<<<1782, 256, 0, stream>>>(x_bf, w_bf, q_bias, v_bias,
                                              q_ws, k_ws, vt_ws);
    attn_kernel<<<9984, 64, 0, stream>>>(q_ws, k_ws, vt_ws, rpb_full, o_ws);
    proj_gemm_kernel<<<594, 256, 0, stream>>>(o_ws, pw_bf, proj_b, out);
}

// Round 10
// 203.210 us; speedup vs baseline: 1.4886x; 1.1006x over previous
//
#include <hip/hip_runtime.h>
#include <hip/hip_bf16.h>

// Problem constants
#define HEADS   12
#define HD      64
#define NTOK    197          // N_PATCH + 1
#define BATCH   64
#define M_TOK   (BATCH*NTOK) // 12608
#define DIMC    768
#define NPAIR   (NTOK*NTOK)  // 38809
#define MPAD    224          // key/m dimension padded to 7*32

typedef __attribute__((ext_vector_type(8))) short bf16x8;  // 8 bf16 (4 VGPRs)
typedef __attribute__((ext_vector_type(4))) short s16x4;
typedef __attribute__((ext_vector_type(4))) float f32x4;

// fp32 -> bf16 round-to-nearest-even
static __device__ __forceinline__ short f2bf(float f) {
    unsigned u = __float_as_uint(f);
    unsigned r = (u + 0x7FFFu + ((u >> 16) & 1u)) >> 16;
    return (short)r;
}

// ---------------------------------------------------------------------------
// Kernel 0a: fused fp32 -> bf16 bulk convert of x, qkv_w, proj_w (one launch)
// ---------------------------------------------------------------------------
#define NX (M_TOK * DIMC)        // 9,682,944
#define NW (3 * DIMC * DIMC)     // 1,769,472
#define NP (DIMC * DIMC)         //   589,824
__global__ void cvt_kernel(const float* __restrict__ s0, short* __restrict__ d0,
                           const float* __restrict__ s1, short* __restrict__ d1,
                           const float* __restrict__ s2, short* __restrict__ d2) {
    int i = (blockIdx.x * 256 + threadIdx.x) * 4;
    const float* s; short* d;
    if (i < NX)                { s = s0 + i; d = d0 + i; }
    else if (i < NX + NW)      { s = s1 + (i - NX); d = d1 + (i - NX); }
    else if (i < NX + NW + NP) { s = s2 + (i - NX - NW); d = d2 + (i - NX - NW); }
    else return;
    const float4 v = *(const float4*)s;
    s16x4 b; b[0] = f2bf(v.x); b[1] = f2bf(v.y); b[2] = f2bf(v.z); b[3] = f2bf(v.w);
    *(s16x4*)d = b;
}

// ---------------------------------------------------------------------------
// Kernel 0b: expand rpb_table via rel_pos_index -> rpb_full[h][n*197+m]
// ---------------------------------------------------------------------------
__global__ void rpb_kernel(const float* __restrict__ table,
                           const int* __restrict__ idx,
                           float* __restrict__ rpb_full) {
    int i = blockIdx.x * 256 + threadIdx.x;
    if (i >= NPAIR) return;
    int id = idx[i];
    #pragma unroll
    for (int h = 0; h < HEADS; ++h)
        rpb_full[(size_t)h * NPAIR + i] = table[id * HEADS + h];
}

// ---------------------------------------------------------------------------
// Shared GEMM building blocks (R7 config): 128x128 tile, BK=64, 4 waves,
// 2-phase double-buffered staging, involution LDS swizzle (conflicts = 0).
// ---------------------------------------------------------------------------
#define STAGE(LA, LB, kt)                                                       \
    _Pragma("unroll")                                                           \
    for (int i = 0; i < 4; ++i) {                                               \
        __builtin_amdgcn_global_load_lds(                                       \
            (const __attribute__((address_space(1))) void*)(aptr[i] + (kt) * 64),\
            (__attribute__((address_space(3))) void*)&(LA)[(wv * 4 + i) * 512], \
            16, 0, 0);                                                          \
        __builtin_amdgcn_global_load_lds(                                       \
            (const __attribute__((address_space(1))) void*)(bptr[i] + (kt) * 64),\
            (__attribute__((address_space(3))) void*)&(LB)[(wv * 4 + i) * 512], \
            16, 0, 0);                                                          \
    }

#define COMPUTE(LA, LB)                                                         \
    _Pragma("unroll")                                                           \
    for (int ks = 0; ks < 2; ++ks) {                                            \
        bf16x8 af[4], bfr[4];                                                   \
        const int kk = (((ks * 4 + g) ^ (c16 & 7)) << 3);   /* swizzled read */ \
        _Pragma("unroll")                                                       \
        for (int i = 0; i < 4; ++i)                                             \
            af[i] = *(const bf16x8*)&(LA)[(wr * 64 + i * 16 + c16) * 64 + kk];  \
        _Pragma("unroll")                                                       \
        for (int j = 0; j < 4; ++j)                                             \
            bfr[j] = *(const bf16x8*)&(LB)[(wc * 64 + j * 16 + c16) * 64 + kk]; \
        _Pragma("unroll")                                                       \
        for (int i = 0; i < 4; ++i)                                             \
            _Pragma("unroll")                                                   \
            for (int j = 0; j < 4; ++j)                                         \
                acc[i][j] = __builtin_amdgcn_mfma_f32_16x16x32_bf16(            \
                    af[i], bfr[j], acc[i][j], 0, 0, 0);                         \
    }

// ---------------------------------------------------------------------------
// Kernel 1: QKV GEMM (bf16 in). which (q/k/v) is UNIFORM per bn: bn 0-5 q,
// 6-11 k, 12-17 v. v-blocks transpose through LDS (reusing the B buffers)
// so vt_ws stores are 128B-contiguous (was: 448B-stride 2B scatter = ~9.7M
// L2 transactions ~ 126 us — the measured 120 us floor).
// Grid: 1782 flat blocks, m204 bijective XCD swizzle (q=222, r=6).
// ---------------------------------------------------------------------------
__global__ __launch_bounds__(256) void qkv_gemm_kernel(
    const short* __restrict__ xb, const short* __restrict__ wb,
    const float* __restrict__ qb, const float* __restrict__ vb,
    short* __restrict__ q_ws, short* __restrict__ k_ws,
    short* __restrict__ vt_ws) {
    __shared__ __align__(16) short lds_a0[128 * 64];
    __shared__ __align__(16) short lds_a1[128 * 64];
    __shared__ __align__(16) short lds_bb[2 * 128 * 64];   // b0 = +0, b1 = +8192
    const int tid  = threadIdx.x;
    const int lane = tid & 63;
    const int wv   = tid >> 6;           // 0..3
    const int wr   = wv >> 1, wc = wv & 1;
    // XCD-bijective decode: nwg=1782, q=222, r=6
    const int flat = blockIdx.x;
    const int xcd  = flat & 7, pos = flat >> 3;
    const int swz  = ((xcd < 6) ? xcd * 223 : 1338 + (xcd - 6) * 222) + pos;
    const int bm   = swz / 18, bn = swz - bm * 18;
    const int g    = lane >> 4, c16 = lane & 15;

    f32x4 acc[4][4] = {};

    const int lrow = lane >> 3;
    const int lcol = ((lane & 7) ^ lrow) * 8;     // inverse-swizzled source col
    const short* aptr[4];
    const short* bptr[4];
    #pragma unroll
    for (int i = 0; i < 4; ++i) {
        const int r  = (wv * 4 + i) * 8 + lrow;
        int gr = bm * 128 + r; if (gr > M_TOK - 1) gr = M_TOK - 1;
        aptr[i] = xb + (size_t)gr * DIMC + lcol;
        bptr[i] = wb + (size_t)(bn * 128 + r) * DIMC + lcol;
    }

    STAGE(lds_a0, lds_bb, 0);
    __syncthreads();
    #pragma unroll
    for (int kp = 0; kp < 6; ++kp) {
        STAGE(lds_a1, (lds_bb + 8192), 2 * kp + 1);
        COMPUTE(lds_a0, lds_bb);
        __syncthreads();
        if (kp < 5) { STAGE(lds_a0, lds_bb, 2 * kp + 2); }
        COMPUTE(lds_a1, (lds_bb + 8192));
        if (kp < 5) __syncthreads();
    }

    // epilogue: C/D layout col = lane&15, row = (lane>>4)*4 + reg  [m89-verified]
    if (bn < 12) {
        const int isq = (bn < 6);
        #pragma unroll
        for (int i = 0; i < 4; ++i) {
            const int tbase = bm * 128 + wr * 64 + i * 16 + (g << 2);
            #pragma unroll
            for (int j = 0; j < 4; ++j) {
                const int c = bn * 128 + wc * 64 + j * 16 + c16;
                const int r = isq ? c : c - DIMC;
                const int h = r >> 6, d = r & 63;
                #pragma unroll
                for (int rg = 0; rg < 4; ++rg) {
                    const int tt = tbase + rg;
                    if (tt >= M_TOK) continue;
                    const int b = tt / NTOK, n = tt - b * NTOK;
                    const size_t bh = (size_t)b * HEADS + h;
                    float val = acc[i][j][rg];
                    if (isq) {
                        val = (val + qb[r]) * 0.125f;                // q scale hd^-0.5
                        q_ws[(bh * NTOK + n) * HD + d] = f2bf(val);
                    } else {
                        k_ws[(bh * NTOK + n) * HD + d] = f2bf(val);
                    }
                }
            }
        }
    } else {
        // v-block: transpose via LDS. Phase A: acc -> LDS[col][tok^sw] (+bias).
        __syncthreads();                  // all waves done reading lds_bb
        short* t = lds_bb;                // 16384 shorts = [128 cols][128 toks]
        #pragma unroll
        for (int i = 0; i < 4; ++i) {
            const int lt0 = wr * 64 + i * 16 + (g << 2);
            #pragma unroll
            for (int j = 0; j < 4; ++j) {
                const int col  = wc * 64 + j * 16 + c16;
                const int sw   = (col & 7) << 3;
                const float bias = vb[(bn - 12) * 128 + col];
                #pragma unroll
                for (int rg = 0; rg < 4; ++rg)
                    t[col * 128 + ((lt0 + rg) ^ sw)] = f2bf(acc[i][j][rg] + bias);
            }
        }
        __syncthreads();
        // Phase B: wave wv streams cols wv,wv+4,...; 64 lanes = 64 consecutive
        // tokens -> contiguous 128B stores.
        for (int cc = 0; cc < 32; ++cc) {
            const int col = cc * 4 + wv;
            const int sw  = (col & 7) << 3;
            const int r   = bn * 128 + col - 1536;
            const int h   = r >> 6, d = r & 63;
            #pragma unroll
            for (int half = 0; half < 2; ++half) {
                const int lt = lane + half * 64;
                const int tt = bm * 128 + lt;
                if (tt < M_TOK) {
                    const int b = tt / NTOK, n = tt - b * NTOK;
                    vt_ws[(((size_t)b * HEADS + h) * HD + d) * MPAD + n] =
                        t[col * 128 + (lt ^ sw)];
                }
            }
        }
    }
}

// ---------------------------------------------------------------------------
// Kernel 2: attention (R9, measured good). 1 wave per (b,h,16-row tile), XCD
// remap, register-BATCHED K / rpb / V loads for memory-level parallelism.
// ---------------------------------------------------------------------------
__global__ __launch_bounds__(64) void attn_kernel(
    const short* __restrict__ q_ws, const short* __restrict__ k_ws,
    const short* __restrict__ vt_ws, const float* __restrict__ rpb_full,
    short* __restrict__ o_ws) {
    __shared__ __align__(16) short p_lds[16 * 232];   // rows padded to 232
    const int lane = threadIdx.x;
    const int id   = blockIdx.x;
    const int slot = id & 7;                          // XCD (round-robin heuristic)
    const int rest = id >> 3;                         // 0..1247
    const int rt   = rest % 13;                       // row tile 0..12
    const int bh   = (rest / 13) * 8 + slot;          // 0..767 (bijective)
    const int b    = bh / HEADS, h = bh - b * HEADS;
    const int g    = lane >> 4, c16 = lane & 15;

    bf16x8 qa0, qa1;
    {
        const size_t base = ((size_t)bh * NTOK + (rt * 16 + c16)) * HD + g * 8;
        qa0 = *(const bf16x8*)(q_ws + base);
        qa1 = *(const bf16x8*)(q_ws + base + 32);
    }

    // batch 1: all 28 K fragments
    bf16x8 kb0[14], kb1[14];
    #pragma unroll
    for (int mt = 0; mt < 14; ++mt) {
        const size_t base = ((size_t)bh * NTOK + (mt * 16 + c16)) * HD + g * 8;
        kb0[mt] = *(const bf16x8*)(k_ws + base);
        kb1[mt] = *(const bf16x8*)(k_ws + base + 32);
    }

    f32x4 sacc[14];
    #pragma unroll
    for (int t = 0; t < 14; ++t) sacc[t] = (f32x4){0.f, 0.f, 0.f, 0.f};
    #pragma unroll
    for (int mt = 0; mt < 14; ++mt) {
        sacc[mt] = __builtin_amdgcn_mfma_f32_16x16x32_bf16(qa0, kb0[mt], sacc[mt], 0, 0, 0);
        sacc[mt] = __builtin_amdgcn_mfma_f32_16x16x32_bf16(qa1, kb1[mt], sacc[mt], 0, 0, 0);
    }

    // batch 2: all 56 rpb values (clamped addresses, masked below)
    float rp[4][14];
    #pragma unroll
    for (int rg = 0; rg < 4; ++rg) {
        int n = rt * 16 + g * 4 + rg; int nc = n > NTOK - 1 ? NTOK - 1 : n;
        const float* rbase = rpb_full + (size_t)h * NPAIR + nc * NTOK;
        #pragma unroll
        for (int mt = 0; mt < 14; ++mt) {
            int m = mt * 16 + c16; int mc = m > NTOK - 1 ? NTOK - 1 : m;
            rp[rg][mt] = rbase[mc];
        }
    }

    float mx[4] = {-1e30f, -1e30f, -1e30f, -1e30f};
    #pragma unroll
    for (int rg = 0; rg < 4; ++rg) {
        const int n = rt * 16 + g * 4 + rg;
        #pragma unroll
        for (int mt = 0; mt < 14; ++mt) {
            const int m = mt * 16 + c16;
            float s = (n < NTOK && m < NTOK) ? sacc[mt][rg] + rp[rg][mt] : -1e30f;
            sacc[mt][rg] = s;
            mx[rg] = fmaxf(mx[rg], s);
        }
    }
    #pragma unroll
    for (int off = 1; off < 16; off <<= 1)
        #pragma unroll
        for (int rg = 0; rg < 4; ++rg)
            mx[rg] = fmaxf(mx[rg], __shfl_xor(mx[rg], off, 64));

    float sm[4] = {0.f, 0.f, 0.f, 0.f};
    #pragma unroll
    for (int mt = 0; mt < 14; ++mt)
        #pragma unroll
        for (int rg = 0; rg < 4; ++rg) {
            float p = exp2f((sacc[mt][rg] - mx[rg]) * 1.44269504f);
            sm[rg] += p;
            p_lds[(g * 4 + rg) * 232 + mt * 16 + c16] = f2bf(p);
        }

    // batch 3: all 28 V fragments (overlap with sum-reduce + waitcnt)
    bf16x8 vbf[7][4];
    #pragma unroll
    for (int ks = 0; ks < 7; ++ks)
        #pragma unroll
        for (int j = 0; j < 4; ++j)
            vbf[ks][j] = *(const bf16x8*)(vt_ws +
                ((size_t)bh * HD + j * 16 + c16) * MPAD + ks * 32 + g * 8);

    #pragma unroll
    for (int off = 1; off < 16; off <<= 1)
        #pragma unroll
        for (int rg = 0; rg < 4; ++rg)
            sm[rg] += __shfl_xor(sm[rg], off, 64);
    __syncthreads();

    f32x4 oacc[4] = {};
    #pragma unroll
    for (int ks = 0; ks < 7; ++ks) {
        const int kk = ks * 32 + g * 8;
        bf16x8 pa = *(const bf16x8*)&p_lds[c16 * 232 + kk];
        #pragma unroll
        for (int j = 0; j < 4; ++j)
            oacc[j] = __builtin_amdgcn_mfma_f32_16x16x32_bf16(pa, vbf[ks][j], oacc[j], 0, 0, 0);
    }

    #pragma unroll
    for (int rg = 0; rg < 4; ++rg) {
        const int n = rt * 16 + g * 4 + rg;
        if (n >= NTOK) continue;
        const float inv = 1.0f / sm[rg];
        #pragma unroll
        for (int j = 0; j < 4; ++j)
            o_ws[((size_t)(b * NTOK + n)) * DIMC + h * HD + j * 16 + c16] =
                f2bf(oacc[j][rg] * inv);
    }
}

// ---------------------------------------------------------------------------
// Kernel 3: proj GEMM (o_ws bf16 @ pw_bf^T + proj_b) -> fp32 out; 2-phase dbuf
// Grid: 594 flat blocks, XCD swizzle (q=74, r=2).
// ---------------------------------------------------------------------------
__global__ __launch_bounds__(256) void proj_gemm_kernel(
    const short* __restrict__ a, const short* __restrict__ wb,
    const float* __restrict__ pb, float* __restrict__ out) {
    __shared__ __align__(16) short lds_a0[128 * 64];
    __shared__ __align__(16) short lds_a1[128 * 64];
    __shared__ __align__(16) short lds_b0[128 * 64];
    __shared__ __align__(16) short lds_b1[128 * 64];
    const int tid  = threadIdx.x;
    const int lane = tid & 63;
    const int wv   = tid >> 6;
    const int wr   = wv >> 1, wc = wv & 1;
    // XCD-bijective decode: nwg=594, q=74, r=2
    const int flat = blockIdx.x;
    const int xcd  = flat & 7, pos = flat >> 3;
    const int swz  = ((xcd < 2) ? xcd * 75 : 150 + (xcd - 2) * 74) + pos;
    const int bm   = swz / 6, bn = swz - bm * 6;
    const int g    = lane >> 4, c16 = lane & 15;

    f32x4 acc[4][4] = {};

    const int lrow = lane >> 3;
    const int lcol = ((lane & 7) ^ lrow) * 8;     // inverse-swizzled source col
    const short* aptr[4];
    const short* bptr[4];
    #pragma unroll
    for (int i = 0; i < 4; ++i) {
        const int r  = (wv * 4 + i) * 8 + lrow;
        int gr = bm * 128 + r; if (gr > M_TOK - 1) gr = M_TOK - 1;
        aptr[i] = a  + (size_t)gr * DIMC + lcol;
        bptr[i] = wb + (size_t)(bn * 128 + r) * DIMC + lcol;
    }

    STAGE(lds_a0, lds_b0, 0);
    __syncthreads();
    #pragma unroll
    for (int kp = 0; kp < 6; ++kp) {
        STAGE(lds_a1, lds_b1, 2 * kp + 1);
        COMPUTE(lds_a0, lds_b0);
        __syncthreads();
        if (kp < 5) { STAGE(lds_a0, lds_b0, 2 * kp + 2); }
        COMPUTE(lds_a1, lds_b1);
        if (kp < 5) __syncthreads();
    }

    #pragma unroll
    for (int i = 0; i < 4; ++i) {
        const int tbase = bm * 128 + wr * 64 + i * 16 + (g << 2);
        #pragma unroll
        for (int j = 0; j < 4; ++j) {
            const int c   = bn * 128 + wc * 64 + j * 16 + c16;
            const float bias = pb[c];
            #pragma unroll
            for (int rg = 0; rg < 4; ++rg) {
                const int tt = tbase + rg;
                if (tt >= M_TOK) continue;
                out[(size_t)tt * DIMC + c] = acc[i][j][rg] + bias;
            }
        }
    }
}

// ---------------------------------------------------------------------------
// Workspace layout (bytes):
//   q_ws   : 19,368,192   @ 0
//   k_ws   : 19,368,192   @ 19,368,192
//   vt_ws  : 22,020,096   @ 38,736,384
//   x_bf / o_ws : 19,365,888 @ 60,756,480  (aliased: x_bf dead before attn)
//   rpb    :  1,862,832   @ 80,122,368
//   w_bf   :  3,538,944   @ 81,985,200
//   pw_bf  :  1,179,648   @ 85,524,144    total 86,703,792
// ---------------------------------------------------------------------------
extern "C" void kernel_launch(void* const* d_in, const int* in_sizes, int n_in,
                              void* d_out, int out_size, void* d_ws, size_t ws_size,
                              hipStream_t stream) {
    const float* x       = (const float*)d_in[0];
    const float* qkv_w   = (const float*)d_in[1];
    const float* q_bias  = (const float*)d_in[2];
    const float* v_bias  = (const float*)d_in[3];
    const float* rpb_tab = (const float*)d_in[4];
    const float* proj_w  = (const float*)d_in[5];
    const float* proj_b  = (const float*)d_in[6];
    const int*   rel_idx = (const int*)d_in[7];
    float* out = (float*)d_out;

    char* ws = (char*)d_ws;
    short* q_ws     = (short*)(ws);
    short* k_ws     = (short*)(ws + 19368192);
    short* vt_ws    = (short*)(ws + 38736384);
    short* x_bf     = (short*)(ws + 60756480);   // aliased with o_ws
    short* o_ws     = (short*)(ws + 60756480);
    float* rpb_full = (float*)(ws + 80122368);
    short* w_bf     = (short*)(ws + 81985200);
    short* pw_bf    = (short*)(ws + 85524144);

    const int ncvt = (NX + NW + NP) / 4;  // 3,010,560 float4 elements
    cvt_kernel<<<(ncvt + 255) / 256, 256, 0, stream>>>(x, x_bf, qkv_w, w_bf, proj_w, pw_bf);
    rpb_kernel<<<(NPAIR + 255) / 256, 256, 0, stream>>>(rpb_tab, rel_idx, rpb_full);

    qkv_gemm_kernel<<<1782, 256, 0, stream>>>(x_bf, w_bf, q_bias, v_bias,
                                              q_ws, k_ws, vt_ws);
    attn_kernel<<<9984, 64, 0, stream>>>(q_ws, k_ws, vt_ws, rpb_full, o_ws);
    proj_gemm_kernel<<<594, 256, 0, stream>>>(o_ws, pw_bf, proj_b, out);
}

// Round 11
// 185.376 us; speedup vs baseline: 1.6318x; 1.0962x over previous
//
#include <hip/hip_runtime.h>
#include <hip/hip_bf16.h>

// Problem constants
#define HEADS   12
#define HD      64
#define NTOK    197          // N_PATCH + 1
#define BATCH   64
#define M_TOK   (BATCH*NTOK) // 12608
#define DIMC    768
#define NPAIR   (NTOK*NTOK)  // 38809
#define MPAD    224          // key/m dimension padded to 7*32

typedef __attribute__((ext_vector_type(8))) short bf16x8;  // 8 bf16 (4 VGPRs)
typedef __attribute__((ext_vector_type(4))) short s16x4;
typedef __attribute__((ext_vector_type(4))) float f32x4;

// fp32 -> bf16 round-to-nearest-even
static __device__ __forceinline__ short f2bf(float f) {
    unsigned u = __float_as_uint(f);
    unsigned r = (u + 0x7FFFu + ((u >> 16) & 1u)) >> 16;
    return (short)r;
}

// ---------------------------------------------------------------------------
// Kernel 0a: fused fp32 -> bf16 bulk convert of x, qkv_w, proj_w (one launch)
// ---------------------------------------------------------------------------
#define NX (M_TOK * DIMC)        // 9,682,944
#define NW (3 * DIMC * DIMC)     // 1,769,472
#define NP (DIMC * DIMC)         //   589,824
__global__ void cvt_kernel(const float* __restrict__ s0, short* __restrict__ d0,
                           const float* __restrict__ s1, short* __restrict__ d1,
                           const float* __restrict__ s2, short* __restrict__ d2) {
    int i = (blockIdx.x * 256 + threadIdx.x) * 4;
    const float* s; short* d;
    if (i < NX)                { s = s0 + i; d = d0 + i; }
    else if (i < NX + NW)      { s = s1 + (i - NX); d = d1 + (i - NX); }
    else if (i < NX + NW + NP) { s = s2 + (i - NX - NW); d = d2 + (i - NX - NW); }
    else return;
    const float4 v = *(const float4*)s;
    s16x4 b; b[0] = f2bf(v.x); b[1] = f2bf(v.y); b[2] = f2bf(v.z); b[3] = f2bf(v.w);
    *(s16x4*)d = b;
}

// ---------------------------------------------------------------------------
// Kernel 0b: expand rpb_table via rel_pos_index -> rpb_full[h][n*197+m]
// ---------------------------------------------------------------------------
__global__ void rpb_kernel(const float* __restrict__ table,
                           const int* __restrict__ idx,
                           float* __restrict__ rpb_full) {
    int i = blockIdx.x * 256 + threadIdx.x;
    if (i >= NPAIR) return;
    int id = idx[i];
    #pragma unroll
    for (int h = 0; h < HEADS; ++h)
        rpb_full[(size_t)h * NPAIR + i] = table[id * HEADS + h];
}

// ---------------------------------------------------------------------------
// Shared GEMM building blocks (R7 config): 128x128 tile, BK=64, 4 waves,
// 2-phase double-buffered staging, involution LDS swizzle (conflicts = 0).
// ---------------------------------------------------------------------------
#define STAGE(LA, LB, kt)                                                       \
    _Pragma("unroll")                                                           \
    for (int i = 0; i < 4; ++i) {                                               \
        __builtin_amdgcn_global_load_lds(                                       \
            (const __attribute__((address_space(1))) void*)(aptr[i] + (kt) * 64),\
            (__attribute__((address_space(3))) void*)&(LA)[(wv * 4 + i) * 512], \
            16, 0, 0);                                                          \
        __builtin_amdgcn_global_load_lds(                                       \
            (const __attribute__((address_space(1))) void*)(bptr[i] + (kt) * 64),\
            (__attribute__((address_space(3))) void*)&(LB)[(wv * 4 + i) * 512], \
            16, 0, 0);                                                          \
    }

#define COMPUTE(LA, LB)                                                         \
    _Pragma("unroll")                                                           \
    for (int ks = 0; ks < 2; ++ks) {                                            \
        bf16x8 af[4], bfr[4];                                                   \
        const int kk = (((ks * 4 + g) ^ (c16 & 7)) << 3);   /* swizzled read */ \
        _Pragma("unroll")                                                       \
        for (int i = 0; i < 4; ++i)                                             \
            af[i] = *(const bf16x8*)&(LA)[(wr * 64 + i * 16 + c16) * 64 + kk];  \
        _Pragma("unroll")                                                       \
        for (int j = 0; j < 4; ++j)                                             \
            bfr[j] = *(const bf16x8*)&(LB)[(wc * 64 + j * 16 + c16) * 64 + kk]; \
        _Pragma("unroll")                                                       \
        for (int i = 0; i < 4; ++i)                                             \
            _Pragma("unroll")                                                   \
            for (int j = 0; j < 4; ++j)                                         \
                acc[i][j] = __builtin_amdgcn_mfma_f32_16x16x32_bf16(            \
                    af[i], bfr[j], acc[i][j], 0, 0, 0);                         \
    }

// ---------------------------------------------------------------------------
// Kernel 1: QKV GEMM (bf16 in). which (q/k/v) is UNIFORM per bn: bn 0-5 q,
// 6-11 k, 12-17 v. ALL paths now transpose through LDS (reusing lds_bb):
//  - q/k: LDS[tok][col] (XOR ((tok>>2)&3)<<4) -> token-row stores, lane = d,
//    128B contiguous; /197 division is wave-uniform (32 scalar divs/wave).
//  - v:   LDS[col][tok] (XOR (col&7)<<3)      -> token-major 128B stores.
// (was: 16-lane d-segments = 4x32B partial-line RMW per instr + 64 per-lane
//  divisions — VALUBusy 20% > MfmaUtil 17.5%.)
// Grid: 1782 flat blocks, m204 bijective XCD swizzle (q=222, r=6).
// ---------------------------------------------------------------------------
__global__ __launch_bounds__(256) void qkv_gemm_kernel(
    const short* __restrict__ xb, const short* __restrict__ wb,
    const float* __restrict__ qb, const float* __restrict__ vb,
    short* __restrict__ q_ws, short* __restrict__ k_ws,
    short* __restrict__ vt_ws) {
    __shared__ __align__(16) short lds_a0[128 * 64];
    __shared__ __align__(16) short lds_a1[128 * 64];
    __shared__ __align__(16) short lds_bb[2 * 128 * 64];   // b0 = +0, b1 = +8192
    const int tid  = threadIdx.x;
    const int lane = tid & 63;
    const int wv   = tid >> 6;           // 0..3
    const int wr   = wv >> 1, wc = wv & 1;
    // XCD-bijective decode: nwg=1782, q=222, r=6
    const int flat = blockIdx.x;
    const int xcd  = flat & 7, pos = flat >> 3;
    const int swz  = ((xcd < 6) ? xcd * 223 : 1338 + (xcd - 6) * 222) + pos;
    const int bm   = swz / 18, bn = swz - bm * 18;
    const int g    = lane >> 4, c16 = lane & 15;

    f32x4 acc[4][4] = {};

    const int lrow = lane >> 3;
    const int lcol = ((lane & 7) ^ lrow) * 8;     // inverse-swizzled source col
    const short* aptr[4];
    const short* bptr[4];
    #pragma unroll
    for (int i = 0; i < 4; ++i) {
        const int r  = (wv * 4 + i) * 8 + lrow;
        int gr = bm * 128 + r; if (gr > M_TOK - 1) gr = M_TOK - 1;
        aptr[i] = xb + (size_t)gr * DIMC + lcol;
        bptr[i] = wb + (size_t)(bn * 128 + r) * DIMC + lcol;
    }

    STAGE(lds_a0, lds_bb, 0);
    __syncthreads();
    #pragma unroll
    for (int kp = 0; kp < 6; ++kp) {
        STAGE(lds_a1, (lds_bb + 8192), 2 * kp + 1);
        COMPUTE(lds_a0, lds_bb);
        __syncthreads();
        if (kp < 5) { STAGE(lds_a0, lds_bb, 2 * kp + 2); }
        COMPUTE(lds_a1, (lds_bb + 8192));
        if (kp < 5) __syncthreads();
    }

    // epilogue: C/D layout col = lane&15, row = (lane>>4)*4 + reg  [m89-verified]
    __syncthreads();                  // all waves done reading lds_bb
    short* t = lds_bb;
    if (bn < 12) {
        const int isq = (bn < 6);
        // Phase A: acc -> t[tok*128 + (col ^ ((tok>>2)&3)<<4)]  (+bias/scale)
        #pragma unroll
        for (int j = 0; j < 4; ++j) {
            const int col = wc * 64 + j * 16 + c16;
            const int r   = isq ? bn * 128 + col : bn * 128 + col - DIMC;
            const float bias = isq ? qb[r] : 0.0f;
            #pragma unroll
            for (int i = 0; i < 4; ++i) {
                const int tok0 = wr * 64 + i * 16 + (g << 2);
                #pragma unroll
                for (int rg = 0; rg < 4; ++rg) {
                    const int tok = tok0 + rg;
                    const int sw  = ((tok >> 2) & 3) << 4;
                    float val = acc[i][j][rg];
                    if (isq) val = (val + bias) * 0.125f;
                    t[tok * 128 + (col ^ sw)] = f2bf(val);
                }
            }
        }
        __syncthreads();
        // Phase B: wave wv streams token rows wv*32..+31; lane = d; 128B stores.
        short* dst = isq ? q_ws : k_ws;
        const int rbase = isq ? bn * 128 : bn * 128 - DIMC;
        for (int tr = 0; tr < 32; ++tr) {
            const int tok = wv * 32 + tr;
            const int tt  = bm * 128 + tok;
            if (tt >= M_TOK) continue;
            const int bb = tt / NTOK, nn = tt - bb * NTOK;     // wave-uniform
            const int sw = ((tok >> 2) & 3) << 4;
            #pragma unroll
            for (int half = 0; half < 2; ++half) {
                const int col = half * 64 + lane;
                const int h   = (rbase + half * 64) >> 6;      // lane<64: no carry
                dst[(((size_t)bb * HEADS + h) * NTOK + nn) * HD + lane] =
                    t[tok * 128 + (col ^ sw)];
            }
        }
    } else {
        // v-block: Phase A: acc -> t[col*128 + (tok ^ (col&7)<<3)] (+bias).
        #pragma unroll
        for (int i = 0; i < 4; ++i) {
            const int lt0 = wr * 64 + i * 16 + (g << 2);
            #pragma unroll
            for (int j = 0; j < 4; ++j) {
                const int col  = wc * 64 + j * 16 + c16;
                const int sw   = (col & 7) << 3;
                const float bias = vb[(bn - 12) * 128 + col];
                #pragma unroll
                for (int rg = 0; rg < 4; ++rg)
                    t[col * 128 + ((lt0 + rg) ^ sw)] = f2bf(acc[i][j][rg] + bias);
            }
        }
        __syncthreads();
        // Phase B: wave wv streams cols wv,wv+4,...; 64 lanes = 64 consecutive
        // tokens -> contiguous 128B stores.
        for (int cc = 0; cc < 32; ++cc) {
            const int col = cc * 4 + wv;
            const int sw  = (col & 7) << 3;
            const int r   = bn * 128 + col - 1536;
            const int h   = r >> 6, d = r & 63;
            #pragma unroll
            for (int half = 0; half < 2; ++half) {
                const int lt = lane + half * 64;
                const int tt = bm * 128 + lt;
                if (tt < M_TOK) {
                    const int b = tt / NTOK, n = tt - b * NTOK;
                    vt_ws[(((size_t)b * HEADS + h) * HD + d) * MPAD + n] =
                        t[col * 128 + (lt ^ sw)];
                }
            }
        }
    }
}

// ---------------------------------------------------------------------------
// Kernel 2: attention (R9, measured good). 1 wave per (b,h,16-row tile), XCD
// remap, register-BATCHED K / rpb / V loads for memory-level parallelism.
// ---------------------------------------------------------------------------
__global__ __launch_bounds__(64) void attn_kernel(
    const short* __restrict__ q_ws, const short* __restrict__ k_ws,
    const short* __restrict__ vt_ws, const float* __restrict__ rpb_full,
    short* __restrict__ o_ws) {
    __shared__ __align__(16) short p_lds[16 * 232];   // rows padded to 232
    const int lane = threadIdx.x;
    const int id   = blockIdx.x;
    const int slot = id & 7;                          // XCD (round-robin heuristic)
    const int rest = id >> 3;                         // 0..1247
    const int rt   = rest % 13;                       // row tile 0..12
    const int bh   = (rest / 13) * 8 + slot;          // 0..767 (bijective)
    const int b    = bh / HEADS, h = bh - b * HEADS;
    const int g    = lane >> 4, c16 = lane & 15;

    bf16x8 qa0, qa1;
    {
        const size_t base = ((size_t)bh * NTOK + (rt * 16 + c16)) * HD + g * 8;
        qa0 = *(const bf16x8*)(q_ws + base);
        qa1 = *(const bf16x8*)(q_ws + base + 32);
    }

    // batch 1: all 28 K fragments
    bf16x8 kb0[14], kb1[14];
    #pragma unroll
    for (int mt = 0; mt < 14; ++mt) {
        const size_t base = ((size_t)bh * NTOK + (mt * 16 + c16)) * HD + g * 8;
        kb0[mt] = *(const bf16x8*)(k_ws + base);
        kb1[mt] = *(const bf16x8*)(k_ws + base + 32);
    }

    f32x4 sacc[14];
    #pragma unroll
    for (int t = 0; t < 14; ++t) sacc[t] = (f32x4){0.f, 0.f, 0.f, 0.f};
    #pragma unroll
    for (int mt = 0; mt < 14; ++mt) {
        sacc[mt] = __builtin_amdgcn_mfma_f32_16x16x32_bf16(qa0, kb0[mt], sacc[mt], 0, 0, 0);
        sacc[mt] = __builtin_amdgcn_mfma_f32_16x16x32_bf16(qa1, kb1[mt], sacc[mt], 0, 0, 0);
    }

    // batch 2: all 56 rpb values (clamped addresses, masked below)
    float rp[4][14];
    #pragma unroll
    for (int rg = 0; rg < 4; ++rg) {
        int n = rt * 16 + g * 4 + rg; int nc = n > NTOK - 1 ? NTOK - 1 : n;
        const float* rbase = rpb_full + (size_t)h * NPAIR + nc * NTOK;
        #pragma unroll
        for (int mt = 0; mt < 14; ++mt) {
            int m = mt * 16 + c16; int mc = m > NTOK - 1 ? NTOK - 1 : m;
            rp[rg][mt] = rbase[mc];
        }
    }

    float mx[4] = {-1e30f, -1e30f, -1e30f, -1e30f};
    #pragma unroll
    for (int rg = 0; rg < 4; ++rg) {
        const int n = rt * 16 + g * 4 + rg;
        #pragma unroll
        for (int mt = 0; mt < 14; ++mt) {
            const int m = mt * 16 + c16;
            float s = (n < NTOK && m < NTOK) ? sacc[mt][rg] + rp[rg][mt] : -1e30f;
            sacc[mt][rg] = s;
            mx[rg] = fmaxf(mx[rg], s);
        }
    }
    #pragma unroll
    for (int off = 1; off < 16; off <<= 1)
        #pragma unroll
        for (int rg = 0; rg < 4; ++rg)
            mx[rg] = fmaxf(mx[rg], __shfl_xor(mx[rg], off, 64));

    float sm[4] = {0.f, 0.f, 0.f, 0.f};
    #pragma unroll
    for (int mt = 0; mt < 14; ++mt)
        #pragma unroll
        for (int rg = 0; rg < 4; ++rg) {
            float p = exp2f((sacc[mt][rg] - mx[rg]) * 1.44269504f);
            sm[rg] += p;
            p_lds[(g * 4 + rg) * 232 + mt * 16 + c16] = f2bf(p);
        }

    // batch 3: all 28 V fragments (overlap with sum-reduce + waitcnt)
    bf16x8 vbf[7][4];
    #pragma unroll
    for (int ks = 0; ks < 7; ++ks)
        #pragma unroll
        for (int j = 0; j < 4; ++j)
            vbf[ks][j] = *(const bf16x8*)(vt_ws +
                ((size_t)bh * HD + j * 16 + c16) * MPAD + ks * 32 + g * 8);

    #pragma unroll
    for (int off = 1; off < 16; off <<= 1)
        #pragma unroll
        for (int rg = 0; rg < 4; ++rg)
            sm[rg] += __shfl_xor(sm[rg], off, 64);
    __syncthreads();

    f32x4 oacc[4] = {};
    #pragma unroll
    for (int ks = 0; ks < 7; ++ks) {
        const int kk = ks * 32 + g * 8;
        bf16x8 pa = *(const bf16x8*)&p_lds[c16 * 232 + kk];
        #pragma unroll
        for (int j = 0; j < 4; ++j)
            oacc[j] = __builtin_amdgcn_mfma_f32_16x16x32_bf16(pa, vbf[ks][j], oacc[j], 0, 0, 0);
    }

    #pragma unroll
    for (int rg = 0; rg < 4; ++rg) {
        const int n = rt * 16 + g * 4 + rg;
        if (n >= NTOK) continue;
        const float inv = 1.0f / sm[rg];
        #pragma unroll
        for (int j = 0; j < 4; ++j)
            o_ws[((size_t)(b * NTOK + n)) * DIMC + h * HD + j * 16 + c16] =
                f2bf(oacc[j][rg] * inv);
    }
}

// ---------------------------------------------------------------------------
// Kernel 3: proj GEMM (o_ws bf16 @ pw_bf^T + proj_b) -> fp32 out; 2-phase dbuf
// Grid: 594 flat blocks, XCD swizzle (q=74, r=2). (fp32 out stores are already
// full-line: 4 toks x 16 cols x 4B = 4 x 64B segments per instr.)
// ---------------------------------------------------------------------------
__global__ __launch_bounds__(256) void proj_gemm_kernel(
    const short* __restrict__ a, const short* __restrict__ wb,
    const float* __restrict__ pb, float* __restrict__ out) {
    __shared__ __align__(16) short lds_a0[128 * 64];
    __shared__ __align__(16) short lds_a1[128 * 64];
    __shared__ __align__(16) short lds_b0[128 * 64];
    __shared__ __align__(16) short lds_b1[128 * 64];
    const int tid  = threadIdx.x;
    const int lane = tid & 63;
    const int wv   = tid >> 6;
    const int wr   = wv >> 1, wc = wv & 1;
    // XCD-bijective decode: nwg=594, q=74, r=2
    const int flat = blockIdx.x;
    const int xcd  = flat & 7, pos = flat >> 3;
    const int swz  = ((xcd < 2) ? xcd * 75 : 150 + (xcd - 2) * 74) + pos;
    const int bm   = swz / 6, bn = swz - bm * 6;
    const int g    = lane >> 4, c16 = lane & 15;

    f32x4 acc[4][4] = {};

    const int lrow = lane >> 3;
    const int lcol = ((lane & 7) ^ lrow) * 8;     // inverse-swizzled source col
    const short* aptr[4];
    const short* bptr[4];
    #pragma unroll
    for (int i = 0; i < 4; ++i) {
        const int r  = (wv * 4 + i) * 8 + lrow;
        int gr = bm * 128 + r; if (gr > M_TOK - 1) gr = M_TOK - 1;
        aptr[i] = a  + (size_t)gr * DIMC + lcol;
        bptr[i] = wb + (size_t)(bn * 128 + r) * DIMC + lcol;
    }

    STAGE(lds_a0, lds_b0, 0);
    __syncthreads();
    #pragma unroll
    for (int kp = 0; kp < 6; ++kp) {
        STAGE(lds_a1, lds_b1, 2 * kp + 1);
        COMPUTE(lds_a0, lds_b0);
        __syncthreads();
        if (kp < 5) { STAGE(lds_a0, lds_b0, 2 * kp + 2); }
        COMPUTE(lds_a1, lds_b1);
        if (kp < 5) __syncthreads();
    }

    #pragma unroll
    for (int i = 0; i < 4; ++i) {
        const int tbase = bm * 128 + wr * 64 + i * 16 + (g << 2);
        #pragma unroll
        for (int j = 0; j < 4; ++j) {
            const int c   = bn * 128 + wc * 64 + j * 16 + c16;
            const float bias = pb[c];
            #pragma unroll
            for (int rg = 0; rg < 4; ++rg) {
                const int tt = tbase + rg;
                if (tt >= M_TOK) continue;
                out[(size_t)tt * DIMC + c] = acc[i][j][rg] + bias;
            }
        }
    }
}

// ---------------------------------------------------------------------------
// Workspace layout (bytes):
//   q_ws   : 19,368,192   @ 0
//   k_ws   : 19,368,192   @ 19,368,192
//   vt_ws  : 22,020,096   @ 38,736,384
//   x_bf / o_ws : 19,365,888 @ 60,756,480  (aliased: x_bf dead before attn)
//   rpb    :  1,862,832   @ 80,122,368
//   w_bf   :  3,538,944   @ 81,985,200
//   pw_bf  :  1,179,648   @ 85,524,144    total 86,703,792
// ---------------------------------------------------------------------------
extern "C" void kernel_launch(void* const* d_in, const int* in_sizes, int n_in,
                              void* d_out, int out_size, void* d_ws, size_t ws_size,
                              hipStream_t stream) {
    const float* x       = (const float*)d_in[0];
    const float* qkv_w   = (const float*)d_in[1];
    const float* q_bias  = (const float*)d_in[2];
    const float* v_bias  = (const float*)d_in[3];
    const float* rpb_tab = (const float*)d_in[4];
    const float* proj_w  = (const float*)d_in[5];
    const float* proj_b  = (const float*)d_in[6];
    const int*   rel_idx = (const int*)d_in[7];
    float* out = (float*)d_out;

    char* ws = (char*)d_ws;
    short* q_ws     = (short*)(ws);
    short* k_ws     = (short*)(ws + 19368192);
    short* vt_ws    = (short*)(ws + 38736384);
    short* x_bf     = (short*)(ws + 60756480);   // aliased with o_ws
    short* o_ws     = (short*)(ws + 60756480);
    float* rpb_full = (float*)(ws + 80122368);
    short* w_bf     = (short*)(ws + 81985200);
    short* pw_bf    = (short*)(ws + 85524144);

    const int ncvt = (NX + NW + NP) / 4;  // 3,010,560 float4 elements
    cvt_kernel<<<(ncvt + 255) / 256, 256, 0, stream>>>(x, x_bf, qkv_w, w_bf, proj_w, pw_bf);
    rpb_kernel<<<(NPAIR + 255) / 256, 256, 0, stream>>>(rpb_tab, rel_idx, rpb_full);

    qkv_gemm_kernel<<<1782, 256, 0, stream>>>(x_bf, w_bf, q_bias, v_bias,
                                              q_ws, k_ws, vt_ws);
    attn_kernel<<<9984, 64, 0, stream>>>(q_ws, k_ws, vt_ws, rpb_full, o_ws);
    proj_gemm_kernel<<<594, 256, 0, stream>>>(o_ws, pw_bf, proj_b, out);
}